// Round 1
// baseline (253.936 us; speedup 1.0000x reference)
//
#include <hip/hip_runtime.h>
#include <hip/hip_bf16.h>

typedef float v4f __attribute__((ext_vector_type(4)));
typedef short v8s __attribute__((ext_vector_type(8)));

// ---- workspace layout (float indices unless _B = byte offset) ----
#define WS_STAT1   0        // 1   (unused now, kept zeroed)
#define WS_STAT2   64       // 64  conv2 per-ic mean-of-max
#define WS_STATL   128      // 1024 linear per-feature sum
#define WS_W1      1152     // 64x28 padded conv1 weights (fp32)
#define WS_B1      2944     // 64
#define WS_B2      3008     // 64
#define WS_WL      3072     // 10x1024 linear weights (fp32)
#define WS_BL      13312    // 10
#define WS_IMAX    13376    // 2048 per-image max|x|
#define WS_WP2_B   61696    // bytes: 25*64*64 bf16 conv2 weights [uv][oc][ic]
#define WS_P1_B    266496   // bytes: 2048*12*12*64 bf16 pooled1 NHWC
#define WS_P2_B    38015232 // bytes: 2048*1024 fp32 pooled2 (NCHW-flat features)
// total ~46.4 MB

__global__ void k_zero(float* ws) {
    int i = blockIdx.x * 256 + threadIdx.x;
    if (i < 1152) ws[i] = 0.f;
}

// per-image max|x| (one wave per image)
__global__ void k_stat1(const float* __restrict__ x, float* ws) {
    int n = blockIdx.x, lane = threadIdx.x;
    const float* p = x + n * 784;
    float m = 0.f;
    for (int i = lane; i < 784; i += 64) m = fmaxf(m, fabsf(p[i]));
#pragma unroll
    for (int off = 32; off; off >>= 1) m = fmaxf(m, __shfl_xor(m, off, 64));
    if (lane == 0) ws[WS_IMAX + n] = m;
}

// conv1 SCINOL weights -> ws[WS_W1] padded [64][28], bias -> ws[WS_B1]
__global__ void k_prepw1(const float* __restrict__ w0, const float* __restrict__ S2,
                         const float* __restrict__ G, const float* __restrict__ eta,
                         const float* __restrict__ wM,
                         const float* __restrict__ b0, const float* __restrict__ bS2,
                         const float* __restrict__ bG, const float* __restrict__ beta,
                         float* ws) {
    __shared__ float red[256];
    int tid = threadIdx.x;
    float p = 0.f;
    for (int i = tid; i < 2048; i += 256) p += ws[WS_IMAX + i];
    red[tid] = p;
    __syncthreads();
    for (int s = 128; s > 0; s >>= 1) {
        if (tid < s) red[tid] += red[tid + s];
        __syncthreads();
    }
    float M = fmaxf(red[0] * (1.f / 2048.f), wM[0]);

    int i = blockIdx.x * 256 + tid;
    if (i < 1792) {
        int ch = i / 28, k = i % 28;
        float v = 0.f;
        if (k < 25) {
            int s = ch * 25 + k;
            float g = G[s];
            float den = sqrtf(S2[s] + M * M);
            float inv = 1.f / den;
            float th = fminf(fmaxf(g * inv, -1.f), 1.f);
            v = w0[s] + ((g != 0.f) ? th * 0.5f * inv * eta[s] : 0.f);
        }
        ws[WS_W1 + i] = v;
    } else if (i < 1856) {
        int c = i - 1792;
        float g = bG[c];
        float den = sqrtf(bS2[c] + 1.f);
        float inv = 1.f / den;
        float th = fminf(fmaxf(g * inv, -1.f), 1.f);
        ws[WS_B1 + c] = b0[c] + ((g != 0.f) ? th * 0.5f * inv * beta[c] : 0.f);
    }
}

// conv1 + bias + relu + 2x2 maxpool + per-channel max stat.
// block = one image, 768 threads: thread (ch = tid&63, pooled-row pr = tid>>6).
__global__ void __launch_bounds__(768, 3)
k_conv1(const float* __restrict__ x, float* ws, __hip_bfloat16* __restrict__ pool1) {
    __shared__ __align__(16) float sX[784];
    __shared__ int sMax[64];
    int n = blockIdx.x, tid = threadIdx.x;
    int ch = tid & 63, pr = tid >> 6;  // pr 0..11
    for (int i = tid; i < 784; i += 768) sX[i] = x[(size_t)n * 784 + i];
    if (tid < 64) sMax[tid] = 0;
    __syncthreads();

    const float* wrow = ws + WS_W1 + ch * 28;
    float w[25];
#pragma unroll
    for (int c = 0; c < 7; ++c) {
        float4 t = ((const float4*)wrow)[c];
        if (4 * c + 0 < 25) w[4 * c + 0] = t.x;
        if (4 * c + 1 < 25) w[4 * c + 1] = t.y;
        if (4 * c + 2 < 25) w[4 * c + 2] = t.z;
        if (4 * c + 3 < 25) w[4 * c + 3] = t.w;
    }
    float b = ws[WS_B1 + ch];

    float acc0[24], acc1[24];
#pragma unroll
    for (int i = 0; i < 24; ++i) { acc0[i] = 0.f; acc1[i] = 0.f; }

#pragma unroll
    for (int r = 0; r < 6; ++r) {  // input rows 2pr..2pr+5
        float rowv[28];
        const float4* rp = (const float4*)&sX[(2 * pr + r) * 28];
#pragma unroll
        for (int c = 0; c < 7; ++c) {
            float4 t = rp[c];
            rowv[4 * c] = t.x; rowv[4 * c + 1] = t.y;
            rowv[4 * c + 2] = t.z; rowv[4 * c + 3] = t.w;
        }
        if (r <= 4) {  // contributes to conv row 2pr with weight row u=r
#pragma unroll
            for (int v = 0; v < 5; ++v)
#pragma unroll
                for (int xx = 0; xx < 24; ++xx)
                    acc0[xx] = fmaf(rowv[xx + v], w[r * 5 + v], acc0[xx]);
        }
        if (r >= 1) {  // contributes to conv row 2pr+1 with weight row u=r-1
#pragma unroll
            for (int v = 0; v < 5; ++v)
#pragma unroll
                for (int xx = 0; xx < 24; ++xx)
                    acc1[xx] = fmaf(rowv[xx + v], w[(r - 1) * 5 + v], acc1[xx]);
        }
    }

    float mymax = 0.f;
    __hip_bfloat16* op = pool1 + ((size_t)n * 144 + pr * 12) * 64 + ch;
#pragma unroll
    for (int px = 0; px < 12; ++px) {
        float m4 = fmaxf(fmaxf(acc0[2 * px], acc0[2 * px + 1]),
                         fmaxf(acc1[2 * px], acc1[2 * px + 1]));
        float pv = fmaxf(m4 + b, 0.f);
        mymax = fmaxf(mymax, pv);
        op[px * 64] = __float2bfloat16(pv);  // NHWC bf16
    }
    atomicMax(&sMax[ch], __float_as_int(mymax));  // pv >= 0 so int-order == float-order
    __syncthreads();
    if (tid < 64) atomicAdd(&ws[WS_STAT2 + tid], __int_as_float(sMax[tid]) * (1.f / 2048.f));
}

// conv2 SCINOL weights -> bf16 [uv][oc][ic]; bias -> ws[WS_B2]
__global__ void k_prepw2(const float* __restrict__ w0, const float* __restrict__ S2,
                         const float* __restrict__ G, const float* __restrict__ eta,
                         const float* __restrict__ wM,
                         const float* __restrict__ b0, const float* __restrict__ bS2,
                         const float* __restrict__ bG, const float* __restrict__ beta,
                         float* ws, __hip_bfloat16* __restrict__ wp2) {
    int i = blockIdx.x * 256 + threadIdx.x;  // exactly 102400
    int uv = i >> 12, rem = i & 4095, oc = rem >> 6, ic = rem & 63;
    int s = oc * 1600 + ic * 25 + uv;
    float M = fmaxf(ws[WS_STAT2 + ic], wM[ic]);
    float g = G[s];
    float den = sqrtf(S2[s] + M * M);
    float inv = 1.f / den;
    float th = fminf(fmaxf(g * inv, -1.f), 1.f);
    float v = w0[s] + ((g != 0.f) ? th * 0.5f * inv * eta[s] : 0.f);
    wp2[i] = __float2bfloat16(v);
    if (blockIdx.x == 0 && threadIdx.x < 64) {
        int c = threadIdx.x;
        float gb = bG[c];
        float den2 = sqrtf(bS2[c] + 1.f);
        float inv2 = 1.f / den2;
        float th2 = fminf(fmaxf(gb * inv2, -1.f), 1.f);
        ws[WS_B2 + c] = b0[c] + ((gb != 0.f) ? th2 * 0.5f * inv2 * beta[c] : 0.f);
    }
}

// conv2 implicit GEMM: block = 128 thr (2 waves), 2 images; wave = 1 image,
// 4x4 tiles of mfma_f32_16x16x32_bf16 (M=64 px, N=64 oc), K-loop over 25 taps x 64 ic.
__global__ void __launch_bounds__(128, 2)
k_conv2(const ushort* __restrict__ pool1, const ushort* __restrict__ wp2,
        const float* __restrict__ ws, float* __restrict__ pool2) {
    __shared__ __align__(16) ushort sImg[2 * 9216];  // 2 images NHWC bf16
    __shared__ __align__(16) ushort sW[4096];        // one tap: [oc][ic]
    int tid = threadIdx.x;
    int wv = tid >> 6, lane = tid & 63;
    int n0 = blockIdx.x * 2;

    {   // stage both images (contiguous 36864 B)
        const uint4* src = (const uint4*)(pool1 + (size_t)n0 * 9216);
        uint4* dst = (uint4*)sImg;
#pragma unroll
        for (int i = 0; i < 18; ++i) dst[tid + i * 128] = src[tid + i * 128];
    }

    int m16 = lane & 15, quad = lane >> 4;
    int q8 = quad * 8;
    int x0 = m16 & 7;
    int yb = m16 >> 3;
    v4f acc[4][4];
#pragma unroll
    for (int i = 0; i < 4; ++i)
#pragma unroll
        for (int j = 0; j < 4; ++j) acc[i][j] = (v4f){0.f, 0.f, 0.f, 0.f};

    const ushort* simg = sImg + wv * 9216;
    int uvIdx = 0;
    for (int u = 0; u < 5; ++u)
        for (int v = 0; v < 5; ++v) {
            __syncthreads();  // prev compute done before overwriting sW
            {
                const uint4* wsrc = (const uint4*)(wp2 + uvIdx * 4096);
                uint4* wdst = (uint4*)sW;
#pragma unroll
                for (int i = 0; i < 4; ++i) wdst[tid + i * 128] = wsrc[tid + i * 128];
            }
            __syncthreads();
            int rb[4];
#pragma unroll
            for (int pt = 0; pt < 4; ++pt)
                rb[pt] = ((pt * 2 + yb + u) * 12 + x0 + v) * 64 + q8;
#pragma unroll
            for (int kc = 0; kc < 2; ++kc) {
                v8s a[4], bf[4];
#pragma unroll
                for (int pt = 0; pt < 4; ++pt)
                    a[pt] = *(const v8s*)(simg + rb[pt] + kc * 32);
#pragma unroll
                for (int ot = 0; ot < 4; ++ot)
                    bf[ot] = *(const v8s*)(sW + (ot * 16 + m16) * 64 + kc * 32 + q8);
#pragma unroll
                for (int pt = 0; pt < 4; ++pt)
#pragma unroll
                    for (int ot = 0; ot < 4; ++ot)
                        acc[pt][ot] = __builtin_amdgcn_mfma_f32_16x16x32_bf16(
                            a[pt], bf[ot], acc[pt][ot], 0, 0, 0);
            }
            ++uvIdx;
        }

    // epilogue: bias + relu + 2x2 maxpool -> pooled2[n][oc*16+py*4+px] fp32
    int n = n0 + wv;
    float bv[4];
#pragma unroll
    for (int ot = 0; ot < 4; ++ot) bv[ot] = ws[WS_B2 + ot * 16 + m16];
    float* outp = pool2 + (size_t)n * 1024;
#pragma unroll
    for (int pt = 0; pt < 4; ++pt)
#pragma unroll
        for (int ot = 0; ot < 4; ++ot) {
            v4f a = acc[pt][ot];
            // lane holds row r=quad*4+reg -> pixel y=pt*2+(quad>>1), x=(quad&1)*4+reg
            float m01 = fmaxf(a[0], a[1]);
            float m23 = fmaxf(a[2], a[3]);
            m01 = fmaxf(m01, __shfl_xor(m01, 32, 64));  // combine y-even/y-odd
            m23 = fmaxf(m23, __shfl_xor(m23, 32, 64));
            if (lane < 32) {
                int oc = ot * 16 + m16;
                int f = oc * 16 + pt * 4 + (quad & 1) * 2;  // py = pt
                outp[f] = fmaxf(m01 + bv[ot], 0.f);
                outp[f + 1] = fmaxf(m23 + bv[ot], 0.f);
            }
        }
}

// per-feature sum over batch (h >= 0 so |h| = h)
__global__ void k_statl(const float* __restrict__ pool2, float* ws) {
    int b = blockIdx.x, tid = threadIdx.x;
    float4 s = {0.f, 0.f, 0.f, 0.f};
    for (int im = 0; im < 32; ++im) {
        float4 v = ((const float4*)(pool2 + (size_t)(b * 32 + im) * 1024))[tid];
        s.x += v.x; s.y += v.y; s.z += v.z; s.w += v.w;
    }
    atomicAdd(&ws[WS_STATL + tid * 4 + 0], s.x);
    atomicAdd(&ws[WS_STATL + tid * 4 + 1], s.y);
    atomicAdd(&ws[WS_STATL + tid * 4 + 2], s.z);
    atomicAdd(&ws[WS_STATL + tid * 4 + 3], s.w);
}

__global__ void k_prepwl(const float* __restrict__ w0, const float* __restrict__ S2,
                         const float* __restrict__ G, const float* __restrict__ eta,
                         const float* __restrict__ wM,
                         const float* __restrict__ b0, const float* __restrict__ bS2,
                         const float* __restrict__ bG, const float* __restrict__ beta,
                         float* ws) {
    int i = blockIdx.x * 256 + threadIdx.x;
    if (i < 10240) {
        int f = i & 1023;
        float stat = ws[WS_STATL + f] * (1.f / 2048.f);
        float M = fmaxf(wM[i], stat);
        float s2 = S2[i];
        float den = sqrtf(s2 + M * M);
        float inv = 1.f / den;
        float th = fminf(fmaxf(G[i] * inv, -1.f), 1.f);
        ws[WS_WL + i] = w0[i] + ((s2 != 0.f) ? th * 0.5f * inv * eta[i] : 0.f);  // cond = wS2 != 0
    } else if (i < 10250) {
        int c = i - 10240;
        float s2 = bS2[c];
        float den = sqrtf(s2 + 1.f);
        float inv = 1.f / den;
        float th = fminf(fmaxf(bG[c] * inv, -1.f), 1.f);
        ws[WS_BL + c] = b0[c] + ((s2 != 0.f) ? th * 0.5f * inv * beta[c] : 0.f);  // cond = bS2 != 0
    }
}

// (2048,1024) x (1024,10)^T + b: wave per image, lane-strided features
__global__ void k_linear(const float* __restrict__ pool2, const float* __restrict__ ws,
                         float* __restrict__ out) {
    int tid = threadIdx.x;
    int wv = tid >> 6, lane = tid & 63;
    int n = blockIdx.x * 4 + wv;
    const float* hp = pool2 + (size_t)n * 1024;
    float h[16];
#pragma unroll
    for (int j = 0; j < 16; ++j) h[j] = hp[j * 64 + lane];
    for (int oc = 0; oc < 10; ++oc) {
        const float* wp = ws + WS_WL + oc * 1024;
        float d = 0.f;
#pragma unroll
        for (int j = 0; j < 16; ++j) d = fmaf(h[j], wp[j * 64 + lane], d);
#pragma unroll
        for (int off = 32; off; off >>= 1) d += __shfl_xor(d, off, 64);
        if (lane == 0) out[n * 10 + oc] = d + ws[WS_BL + oc];
    }
}

extern "C" void kernel_launch(void* const* d_in, const int* in_sizes, int n_in,
                              void* d_out, int out_size, void* d_ws, size_t ws_size,
                              hipStream_t stream) {
    const float* x = (const float*)d_in[0];
    float* ws = (float*)d_ws;
    __hip_bfloat16* wp2 = (__hip_bfloat16*)((char*)d_ws + WS_WP2_B);
    __hip_bfloat16* p1 = (__hip_bfloat16*)((char*)d_ws + WS_P1_B);
    float* p2 = (float*)((char*)d_ws + WS_P2_B);
    float* out = (float*)d_out;

    k_zero<<<5, 256, 0, stream>>>(ws);
    k_stat1<<<2048, 64, 0, stream>>>(x, ws);
    k_prepw1<<<8, 256, 0, stream>>>(
        (const float*)d_in[1], (const float*)d_in[2], (const float*)d_in[3],
        (const float*)d_in[4], (const float*)d_in[5], (const float*)d_in[6],
        (const float*)d_in[7], (const float*)d_in[8], (const float*)d_in[9], ws);
    k_conv1<<<2048, 768, 0, stream>>>(x, ws, p1);
    k_prepw2<<<400, 256, 0, stream>>>(
        (const float*)d_in[10], (const float*)d_in[11], (const float*)d_in[12],
        (const float*)d_in[13], (const float*)d_in[14], (const float*)d_in[15],
        (const float*)d_in[16], (const float*)d_in[17], (const float*)d_in[18], ws, wp2);
    k_conv2<<<1024, 128, 0, stream>>>((const ushort*)p1, (const ushort*)wp2, ws, p2);
    k_statl<<<64, 256, 0, stream>>>(p2, ws);
    k_prepwl<<<41, 256, 0, stream>>>(
        (const float*)d_in[19], (const float*)d_in[20], (const float*)d_in[21],
        (const float*)d_in[22], (const float*)d_in[23], (const float*)d_in[24],
        (const float*)d_in[25], (const float*)d_in[26], (const float*)d_in[27], ws);
    k_linear<<<512, 256, 0, stream>>>(p2, ws, out);
}